// Round 1
// baseline (4562.859 us; speedup 1.0000x reference)
//
#include <hip/hip_runtime.h>
#include <math.h>

#define B_ 32
#define M_ 512
#define N_ 512
#define E_ 768

#define GBM 128
#define GBN 128
#define GBK 16

#define NEG_BIG   -1e12f
#define INV_SCALE 0.03608439182435161f  // 1/sqrt(768)

// ---------------------------------------------------------------------------
// GEMM 1 (NT): att[b,m,n] = mask ? dot(c_hs[b,m,:], r_hs[b,n,:])/sqrt(E) : -1e12
// ---------------------------------------------------------------------------
__global__ __launch_bounds__(256, 2)
void gemm_att_kernel(const float* __restrict__ chs, const float* __restrict__ rhs,
                     const int* __restrict__ cids, const int* __restrict__ rids,
                     float* __restrict__ att)
{
    __shared__ float As[GBK][GBM + 4];
    __shared__ float Bs[GBK][GBN + 4];
    const int b  = blockIdx.z;
    const int m0 = blockIdx.x * GBM;
    const int n0 = blockIdx.y * GBN;
    const int tid = threadIdx.x;
    const int tx = tid & 15, ty = tid >> 4;
    const float* Ab = chs + (size_t)b * M_ * E_;
    const float* Bb = rhs + (size_t)b * N_ * E_;
    const int sr = tid >> 1;          // staging row 0..127
    const int sk = (tid & 1) << 3;    // k offset 0 or 8

    float acc[8][8];
#pragma unroll
    for (int i = 0; i < 8; ++i)
#pragma unroll
        for (int j = 0; j < 8; ++j) acc[i][j] = 0.f;

    for (int k0 = 0; k0 < E_; k0 += GBK) {
        const float* ap = Ab + (size_t)(m0 + sr) * E_ + k0 + sk;
        const float* bp = Bb + (size_t)(n0 + sr) * E_ + k0 + sk;
        float4 a0 = *(const float4*)(ap);
        float4 a1 = *(const float4*)(ap + 4);
        float4 b0 = *(const float4*)(bp);
        float4 b1 = *(const float4*)(bp + 4);
        __syncthreads();
        As[sk+0][sr]=a0.x; As[sk+1][sr]=a0.y; As[sk+2][sr]=a0.z; As[sk+3][sr]=a0.w;
        As[sk+4][sr]=a1.x; As[sk+5][sr]=a1.y; As[sk+6][sr]=a1.z; As[sk+7][sr]=a1.w;
        Bs[sk+0][sr]=b0.x; Bs[sk+1][sr]=b0.y; Bs[sk+2][sr]=b0.z; Bs[sk+3][sr]=b0.w;
        Bs[sk+4][sr]=b1.x; Bs[sk+5][sr]=b1.y; Bs[sk+6][sr]=b1.z; Bs[sk+7][sr]=b1.w;
        __syncthreads();
#pragma unroll
        for (int kk = 0; kk < GBK; ++kk) {
            float af[8], bf[8];
            *(float4*)&af[0] = *(const float4*)&As[kk][ty*4];
            *(float4*)&af[4] = *(const float4*)&As[kk][64 + ty*4];
            *(float4*)&bf[0] = *(const float4*)&Bs[kk][tx*4];
            *(float4*)&bf[4] = *(const float4*)&Bs[kk][64 + tx*4];
#pragma unroll
            for (int i = 0; i < 8; ++i)
#pragma unroll
                for (int j = 0; j < 8; ++j)
                    acc[i][j] = fmaf(af[i], bf[j], acc[i][j]);
        }
    }

    bool rmv[8];
    int  cols[8];
#pragma unroll
    for (int j = 0; j < 8; ++j) {
        cols[j] = n0 + tx*4 + (j & 3) + ((j >> 2) << 6);
        rmv[j]  = rids[b * N_ + cols[j]] != 0;
    }
    float* Cb = att + (size_t)b * M_ * N_;
#pragma unroll
    for (int i = 0; i < 8; ++i) {
        int row = m0 + ty*4 + (i & 3) + ((i >> 2) << 6);
        bool cm = cids[b * M_ + row] != 0;
        float v[8];
#pragma unroll
        for (int j = 0; j < 8; ++j)
            v[j] = (cm && rmv[j]) ? acc[i][j] * INV_SCALE : NEG_BIG;
        *(float4*)(Cb + (size_t)row * N_ + n0 + tx*4)      = make_float4(v[0],v[1],v[2],v[3]);
        *(float4*)(Cb + (size_t)row * N_ + n0 + 64 + tx*4) = make_float4(v[4],v[5],v[6],v[7]);
    }
}

// ---------------------------------------------------------------------------
// GEMM NN (per batch): C[b] = A[b] (512x512) @ Bm[b] (512x768)
// used for c_hat = P1 @ r_hs and r_hat = P2t @ c_hs
// ---------------------------------------------------------------------------
__global__ __launch_bounds__(256, 2)
void gemm_nn_kernel(const float* __restrict__ A, const float* __restrict__ Bm,
                    float* __restrict__ C)
{
    __shared__ float As[GBK][GBM + 4];
    __shared__ float Bs[GBK][GBN + 4];
    const int b  = blockIdx.z;
    const int m0 = blockIdx.x * GBM;   // over 512
    const int n0 = blockIdx.y * GBN;   // over 768
    const int tid = threadIdx.x;
    const int tx = tid & 15, ty = tid >> 4;
    const float* Ab = A  + (size_t)b * M_ * N_;
    const float* Bb = Bm + (size_t)b * N_ * E_;
    const int sra = tid >> 1,  ska = (tid & 1) << 3;   // A staging (transposed)
    const int skb = tid >> 4,  snb = (tid & 15) << 3;  // B staging (direct)

    float acc[8][8];
#pragma unroll
    for (int i = 0; i < 8; ++i)
#pragma unroll
        for (int j = 0; j < 8; ++j) acc[i][j] = 0.f;

    for (int k0 = 0; k0 < N_; k0 += GBK) {
        const float* ap = Ab + (size_t)(m0 + sra) * N_ + k0 + ska;
        float4 a0 = *(const float4*)(ap);
        float4 a1 = *(const float4*)(ap + 4);
        const float* bp = Bb + (size_t)(k0 + skb) * E_ + n0 + snb;
        float4 b0 = *(const float4*)(bp);
        float4 b1 = *(const float4*)(bp + 4);
        __syncthreads();
        As[ska+0][sra]=a0.x; As[ska+1][sra]=a0.y; As[ska+2][sra]=a0.z; As[ska+3][sra]=a0.w;
        As[ska+4][sra]=a1.x; As[ska+5][sra]=a1.y; As[ska+6][sra]=a1.z; As[ska+7][sra]=a1.w;
        *(float4*)&Bs[skb][snb]     = b0;
        *(float4*)&Bs[skb][snb + 4] = b1;
        __syncthreads();
#pragma unroll
        for (int kk = 0; kk < GBK; ++kk) {
            float af[8], bf[8];
            *(float4*)&af[0] = *(const float4*)&As[kk][ty*4];
            *(float4*)&af[4] = *(const float4*)&As[kk][64 + ty*4];
            *(float4*)&bf[0] = *(const float4*)&Bs[kk][tx*4];
            *(float4*)&bf[4] = *(const float4*)&Bs[kk][64 + tx*4];
#pragma unroll
            for (int i = 0; i < 8; ++i)
#pragma unroll
                for (int j = 0; j < 8; ++j)
                    acc[i][j] = fmaf(af[i], bf[j], acc[i][j]);
        }
    }

    float* Cb = C + (size_t)b * M_ * E_;
#pragma unroll
    for (int i = 0; i < 8; ++i) {
        int row = m0 + ty*4 + (i & 3) + ((i >> 2) << 6);
        *(float4*)(Cb + (size_t)row * E_ + n0 + tx*4)      = make_float4(acc[i][0],acc[i][1],acc[i][2],acc[i][3]);
        *(float4*)(Cb + (size_t)row * E_ + n0 + 64 + tx*4) = make_float4(acc[i][4],acc[i][5],acc[i][6],acc[i][7]);
    }
}

// ---------------------------------------------------------------------------
// GEMM with on-the-fly submult features:
// OUT[r, j] = relu(b_pre[j] + sum_k feat(HAT[r],HS[r])[k] * W[k,j]),  K = 5*E
// rows r flattened over [B*rows, E]; feature segment = k/E:
//   0: a   1: b   2: a-b   3: a*b   4: (a-b)^2     (a=HAT, b=HS)
// ---------------------------------------------------------------------------
__global__ __launch_bounds__(256, 2)
void gemm_feat_kernel(const float* __restrict__ HAT, const float* __restrict__ HS,
                      const float* __restrict__ W, const float* __restrict__ bias,
                      float* __restrict__ OUT)
{
    __shared__ float As[GBK][GBM + 4];
    __shared__ float Bs[GBK][GBN + 4];
    const int m0 = blockIdx.x * GBM;   // over 16384
    const int n0 = blockIdx.y * GBN;   // over 768
    const int tid = threadIdx.x;
    const int tx = tid & 15, ty = tid >> 4;
    const int sra = tid >> 1,  ska = (tid & 1) << 3;
    const int skb = tid >> 4,  snb = (tid & 15) << 3;

    float acc[8][8];
#pragma unroll
    for (int i = 0; i < 8; ++i)
#pragma unroll
        for (int j = 0; j < 8; ++j) acc[i][j] = 0.f;

    for (int k0 = 0; k0 < 5 * E_; k0 += GBK) {
        const int seg = k0 / E_;                   // uniform over block
        const int e0  = k0 - seg * E_ + ska;
        const size_t ro = (size_t)(m0 + sra) * E_ + e0;
        float4 h0 = *(const float4*)(HAT + ro);
        float4 h1 = *(const float4*)(HAT + ro + 4);
        float4 s0 = *(const float4*)(HS + ro);
        float4 s1 = *(const float4*)(HS + ro + 4);
        float fa[8] = {h0.x,h0.y,h0.z,h0.w,h1.x,h1.y,h1.z,h1.w};
        float fb[8] = {s0.x,s0.y,s0.z,s0.w,s1.x,s1.y,s1.z,s1.w};
        float f[8];
#pragma unroll
        for (int t = 0; t < 8; ++t) {
            float d = fa[t] - fb[t];
            f[t] = (seg == 0) ? fa[t]
                 : (seg == 1) ? fb[t]
                 : (seg == 2) ? d
                 : (seg == 3) ? fa[t] * fb[t]
                 :              d * d;
        }
        const float* wp = W + (size_t)(k0 + skb) * E_ + n0 + snb;
        float4 b0 = *(const float4*)(wp);
        float4 b1 = *(const float4*)(wp + 4);
        __syncthreads();
#pragma unroll
        for (int t = 0; t < 8; ++t) As[ska + t][sra] = f[t];
        *(float4*)&Bs[skb][snb]     = b0;
        *(float4*)&Bs[skb][snb + 4] = b1;
        __syncthreads();
#pragma unroll
        for (int kk = 0; kk < GBK; ++kk) {
            float af[8], bf[8];
            *(float4*)&af[0] = *(const float4*)&As[kk][ty*4];
            *(float4*)&af[4] = *(const float4*)&As[kk][64 + ty*4];
            *(float4*)&bf[0] = *(const float4*)&Bs[kk][tx*4];
            *(float4*)&bf[4] = *(const float4*)&Bs[kk][64 + tx*4];
#pragma unroll
            for (int i = 0; i < 8; ++i)
#pragma unroll
                for (int j = 0; j < 8; ++j)
                    acc[i][j] = fmaf(af[i], bf[j], acc[i][j]);
        }
    }

    float bv[8];
#pragma unroll
    for (int j = 0; j < 8; ++j)
        bv[j] = bias[n0 + tx*4 + (j & 3) + ((j >> 2) << 6)];
#pragma unroll
    for (int i = 0; i < 8; ++i) {
        int row = m0 + ty*4 + (i & 3) + ((i >> 2) << 6);
        float v[8];
#pragma unroll
        for (int j = 0; j < 8; ++j) v[j] = fmaxf(acc[i][j] + bv[j], 0.f);
        *(float4*)(OUT + (size_t)row * E_ + n0 + tx*4)      = make_float4(v[0],v[1],v[2],v[3]);
        *(float4*)(OUT + (size_t)row * E_ + n0 + 64 + tx*4) = make_float4(v[4],v[5],v[6],v[7]);
    }
}

// ---------------------------------------------------------------------------
// Row softmax over last axis: one wave per row (4 rows / block)
// ---------------------------------------------------------------------------
__global__ __launch_bounds__(256)
void softmax_rows(const float* __restrict__ att, float* __restrict__ P)
{
    const int wave = threadIdx.x >> 6;
    const int lane = threadIdx.x & 63;
    const size_t row = (size_t)blockIdx.x * 4 + wave;   // over B*M
    const float* x = att + row * N_;
    float v[8];
    float mx = -INFINITY;
#pragma unroll
    for (int i = 0; i < 8; ++i) { v[i] = x[lane + i * 64]; mx = fmaxf(mx, v[i]); }
#pragma unroll
    for (int off = 32; off; off >>= 1) mx = fmaxf(mx, __shfl_xor(mx, off));
    float s = 0.f;
#pragma unroll
    for (int i = 0; i < 8; ++i) { v[i] = __expf(v[i] - mx); s += v[i]; }
#pragma unroll
    for (int off = 32; off; off >>= 1) s += __shfl_xor(s, off);
    const float inv = 1.f / s;
    float* y = P + row * N_;
#pragma unroll
    for (int i = 0; i < 8; ++i) y[lane + i * 64] = v[i] * inv;
}

// ---------------------------------------------------------------------------
// Column softmax (over m) with transposed output: P2t[b,n,m] = softmax_m(att[b,m,n])
// 16 columns per block, full 512-row tile staged in LDS.
// ---------------------------------------------------------------------------
__global__ __launch_bounds__(256)
void softmax_cols_t(const float* __restrict__ att, float* __restrict__ P2t)
{
    __shared__ float tile[512][17];
    __shared__ float red[16][16];
    __shared__ float invs[16];
    const int b  = blockIdx.x;
    const int n0 = blockIdx.y * 16;
    const int tid = threadIdx.x;
    const int c = tid & 15, r = tid >> 4;
    const float* src = att + (size_t)b * M_ * N_ + n0;
#pragma unroll 4
    for (int i = 0; i < 32; ++i) {
        int m = r + i * 16;
        tile[m][c] = src[(size_t)m * N_ + c];
    }
    __syncthreads();
    float mx = -INFINITY;
    for (int m = r; m < 512; m += 16) mx = fmaxf(mx, tile[m][c]);
    red[r][c] = mx;
    __syncthreads();
    if (r == 0) {
        float m2 = red[0][c];
#pragma unroll
        for (int j = 1; j < 16; ++j) m2 = fmaxf(m2, red[j][c]);
        invs[c] = m2;
    }
    __syncthreads();
    const float cmx = invs[c];
    float s = 0.f;
    for (int m = r; m < 512; m += 16) {
        float e = __expf(tile[m][c] - cmx);
        tile[m][c] = e;
        s += e;
    }
    __syncthreads();
    red[r][c] = s;
    __syncthreads();
    if (r == 0) {
        float st = 0.f;
#pragma unroll
        for (int j = 0; j < 16; ++j) st += red[j][c];
        invs[c] = 1.f / st;
    }
    __syncthreads();
    float* dst = P2t + ((size_t)b * N_ + n0) * M_;
#pragma unroll 4
    for (int i = 0; i < 32; ++i) {
        int lin = tid + i * 256;       // over 16*512
        int cc = lin >> 9;
        int m  = lin & 511;
        dst[(size_t)cc * M_ + m] = tile[m][cc] * invs[cc];
    }
}

// ---------------------------------------------------------------------------
// Masked feature reduction: feat[b] = [x[0,:], sum(x)/cnt, max(x)], x = mask? bar : 0
// grid (B, 3), 256 threads; channel e = blockIdx.y*256 + tid
// ---------------------------------------------------------------------------
__global__ __launch_bounds__(256)
void reduce_feat(const float* __restrict__ bar, const int* __restrict__ ids,
                 float* __restrict__ feat)
{
    const int b = blockIdx.x;
    const int e = blockIdx.y * 256 + threadIdx.x;
    const float* src = bar + ((size_t)b * 512) * E_ + e;
    const int* idb = ids + b * 512;
    float first = 0.f, sum = 0.f, mx = -INFINITY;
    int cnt = 0;
#pragma unroll 4
    for (int m = 0; m < 512; ++m) {
        const int idv = idb[m];
        const float raw = src[(size_t)m * E_];
        const bool valid = idv != 0;
        const float v = valid ? raw : 0.f;
        if (m == 0) first = v;
        sum += v;
        mx = fmaxf(mx, v);
        cnt += valid ? 1 : 0;
    }
    float* fb = feat + (size_t)b * 3 * E_;
    fb[e]            = first;
    fb[E_ + e]       = sum / (float)cnt;
    fb[2 * E_ + e]   = mx;
}

// ---------------------------------------------------------------------------
// h[b,j] = relu(b_ff1[j] + sum_k submult(c_feat,r_feat)[k] * W_ff1[k,j])
// grid (B, 3); K = 5*2304 = 11520
// ---------------------------------------------------------------------------
__global__ __launch_bounds__(256)
void ff1_kernel(const float* __restrict__ cfeat, const float* __restrict__ rfeat,
                const float* __restrict__ W1, const float* __restrict__ b1,
                float* __restrict__ h)
{
    __shared__ float cf[3 * E_];
    __shared__ float rf[3 * E_];
    const int b = blockIdx.x;
    const int tid = threadIdx.x;
    for (int i = tid; i < 3 * E_; i += 256) {
        cf[i] = cfeat[(size_t)b * 3 * E_ + i];
        rf[i] = rfeat[(size_t)b * 3 * E_ + i];
    }
    __syncthreads();
    const int j = blockIdx.y * 256 + tid;
    float acc = b1[j];
    const float* Wj = W1 + j;
#pragma unroll
    for (int seg = 0; seg < 5; ++seg) {
        const float* Wk = Wj + (size_t)seg * (3 * E_) * E_;
#pragma unroll 8
        for (int e = 0; e < 3 * E_; ++e) {
            const float a = cf[e], bb = rf[e];
            const float d = a - bb;
            const float mv = (seg == 0) ? a
                           : (seg == 1) ? bb
                           : (seg == 2) ? d
                           : (seg == 3) ? a * bb
                           :              d * d;
            acc = fmaf(mv, Wk[(size_t)e * E_], acc);
        }
    }
    h[(size_t)b * E_ + j] = fmaxf(acc, 0.f);
}

// ---------------------------------------------------------------------------
// scores[b] = b_ff2 + sum_j h[b,j] * W_ff2[j]
// ---------------------------------------------------------------------------
__global__ __launch_bounds__(256)
void score_kernel(const float* __restrict__ h, const float* __restrict__ W2,
                  const float* __restrict__ b2, float* __restrict__ out)
{
    const int b = blockIdx.x;
    const int tid = threadIdx.x;
    float acc = 0.f;
    for (int j = tid; j < E_; j += 256) acc += h[(size_t)b * E_ + j] * W2[j];
#pragma unroll
    for (int off = 32; off; off >>= 1) acc += __shfl_xor(acc, off);
    __shared__ float red[4];
    if ((tid & 63) == 0) red[tid >> 6] = acc;
    __syncthreads();
    if (tid == 0) out[b] = red[0] + red[1] + red[2] + red[3] + b2[0];
}

// ---------------------------------------------------------------------------
extern "C" void kernel_launch(void* const* d_in, const int* in_sizes, int n_in,
                              void* d_out, int out_size, void* d_ws, size_t ws_size,
                              hipStream_t stream)
{
    const int*   c_ids = (const int*)d_in[0];
    const int*   r_ids = (const int*)d_in[1];
    const float* c_hs  = (const float*)d_in[2];
    const float* r_hs  = (const float*)d_in[3];
    const float* W_pre = (const float*)d_in[4];
    const float* b_pre = (const float*)d_in[5];
    const float* W_ff1 = (const float*)d_in[6];
    const float* b_ff1 = (const float*)d_in[7];
    const float* W_ff2 = (const float*)d_in[8];
    const float* b_ff2 = (const float*)d_in[9];
    float* out = (float*)d_out;
    float* ws  = (float*)d_ws;

    const size_t SZ_ATT = (size_t)B_ * M_ * N_;   // 8,388,608 floats
    const size_t SZ_CH  = (size_t)B_ * M_ * E_;   // 12,582,912 floats

    // Aliased workspace layout (stream-ordered lifetimes; peak = 144.7 MiB):
    float* att   = ws;                        // [0, ATT)            dead after col-softmax
    float* P1    = ws + SZ_ATT;               // [ATT, 2ATT)         dead after c_hat GEMM
    float* P2t   = ws + 2 * SZ_ATT;           // [2ATT, 3ATT)        dead after r_hat GEMM
    float* chat  = ws + 3 * SZ_ATT;           // [3ATT, 3ATT+CH)     dead after c_bar GEMM
    float* rhat  = ws;                        // alias att+P1 (both dead when written)
    float* cbar  = ws + SZ_CH;                // alias P1-tail+P2t (dead when written)
    float* rbar  = ws + 3 * SZ_ATT;           // alias chat (dead when written)
    float* cfeat = ws + 3 * SZ_ATT + SZ_CH;
    float* rfeat = cfeat + (size_t)B_ * 3 * E_;
    float* hbuf  = rfeat + (size_t)B_ * 3 * E_;

    // 1. attention logits (masked, scaled)
    gemm_att_kernel<<<dim3(M_/GBM, N_/GBN, B_), 256, 0, stream>>>(c_hs, r_hs, c_ids, r_ids, att);
    // 2. softmax over n -> P1 ; softmax over m (transposed out) -> P2t
    softmax_rows  <<<dim3(B_ * M_ / 4), 256, 0, stream>>>(att, P1);
    softmax_cols_t<<<dim3(B_, N_ / 16), 256, 0, stream>>>(att, P2t);
    // 3. c_hat = P1 @ r_hs ; r_hat = P2t @ c_hs
    gemm_nn_kernel<<<dim3(M_/GBM, E_/GBN, B_), 256, 0, stream>>>(P1, r_hs, chat);
    gemm_nn_kernel<<<dim3(N_/GBM, E_/GBN, B_), 256, 0, stream>>>(P2t, c_hs, rhat);
    // 4. c_bar / r_bar = relu(submult(.,.) @ W_pre + b_pre), fused feature GEMM
    gemm_feat_kernel<<<dim3(B_*M_/GBM, E_/GBN), 256, 0, stream>>>(chat, c_hs, W_pre, b_pre, cbar);
    reduce_feat     <<<dim3(B_, 3), 256, 0, stream>>>(cbar, c_ids, cfeat);
    gemm_feat_kernel<<<dim3(B_*N_/GBM, E_/GBN), 256, 0, stream>>>(rhat, r_hs, W_pre, b_pre, rbar);
    reduce_feat     <<<dim3(B_, 3), 256, 0, stream>>>(rbar, r_ids, rfeat);
    // 5. FF head
    ff1_kernel  <<<dim3(B_, 3), 256, 0, stream>>>(cfeat, rfeat, W_ff1, b_ff1, hbuf);
    score_kernel<<<dim3(B_), 256, 0, stream>>>(hbuf, W_ff2, b_ff2, out);
}

// Round 4
// 1394.399 us; speedup vs baseline: 3.2723x; 3.2723x over previous
//
#include <hip/hip_runtime.h>
#include <math.h>

#define B_ 32
#define M_ 512
#define N_ 512
#define E_ 768
#define NEG_BIG   -1e12f
#define INV_SCALE 0.03608439182435161f  // 1/sqrt(768)

typedef __attribute__((ext_vector_type(8))) __bf16 bf16x8;
typedef __attribute__((ext_vector_type(4))) float  floatx4;

#define MFMA_BF16 __builtin_amdgcn_mfma_f32_16x16x32_bf16

// ---------------------------------------------------------------------------
// helpers: load 16 floats; split-bf16 convert + swizzled LDS store of 16 elems
// LDS tile layout: [128 rows][32 k] bf16 (64B rows); 16B slot s swizzled by
// s ^= (row>>1)&3  (spreads the 4-slot row across banks; residual 2-way on
// b128 reads is free per m136).
// ---------------------------------------------------------------------------
__device__ __forceinline__ void load16(const float* __restrict__ p, float* v) {
    *(float4*)&v[0]  = *(const float4*)(p);
    *(float4*)&v[4]  = *(const float4*)(p + 4);
    *(float4*)&v[8]  = *(const float4*)(p + 8);
    *(float4*)&v[12] = *(const float4*)(p + 12);
}

__device__ __forceinline__ void cvt_store16(const float* v, __bf16* hi, __bf16* lo,
                                            int row, int h) {
    bf16x8 h0, h1, l0, l1;
#pragma unroll
    for (int j = 0; j < 8; ++j) {
        float x0 = v[j], x1 = v[j + 8];
        __bf16 a0 = (__bf16)x0;
        __bf16 a1 = (__bf16)x1;
        h0[j] = a0;
        h1[j] = a1;
        l0[j] = (__bf16)(x0 - (float)a0);
        l1[j] = (__bf16)(x1 - (float)a1);
    }
    const int xr = (row >> 1) & 3;
    *(bf16x8*)&hi[row * 32 + (((2 * h)     ^ xr) << 3)] = h0;
    *(bf16x8*)&hi[row * 32 + (((2 * h + 1) ^ xr) << 3)] = h1;
    *(bf16x8*)&lo[row * 32 + (((2 * h)     ^ xr) << 3)] = l0;
    *(bf16x8*)&lo[row * 32 + (((2 * h + 1) ^ xr) << 3)] = l1;
}

// one BK=32 step: 16 LDS frag loads + 48 MFMAs (hi*hi + hi*lo + lo*hi)
__device__ __forceinline__ void mfma_step(const __bf16* Ahi, const __bf16* Alo,
                                          const __bf16* Bhi, const __bf16* Blo,
                                          const int (&aoff)[4], const int (&boff)[4],
                                          floatx4 (&acc)[4][4]) {
    bf16x8 bh[4], bl[4];
#pragma unroll
    for (int fn = 0; fn < 4; ++fn) {
        bh[fn] = *(const bf16x8*)&Bhi[boff[fn]];
        bl[fn] = *(const bf16x8*)&Blo[boff[fn]];
    }
#pragma unroll
    for (int fm = 0; fm < 4; ++fm) {
        bf16x8 ah = *(const bf16x8*)&Ahi[aoff[fm]];
        bf16x8 al = *(const bf16x8*)&Alo[aoff[fm]];
#pragma unroll
        for (int fn = 0; fn < 4; ++fn) {
            acc[fm][fn] = MFMA_BF16(ah, bh[fn], acc[fm][fn], 0, 0, 0);
            acc[fm][fn] = MFMA_BF16(ah, bl[fn], acc[fm][fn], 0, 0, 0);
            acc[fm][fn] = MFMA_BF16(al, bh[fn], acc[fm][fn], 0, 0, 0);
        }
    }
}

#define TILE_SETUP()                                                      \
    const int tid = threadIdx.x, lane = tid & 63;                         \
    const int l15 = lane & 15, l4 = lane >> 4;                            \
    const int wid = tid >> 6, wm = wid >> 1, wn = wid & 1;                \
    const int srow = tid >> 1, h = tid & 1;                               \
    int aoff[4], boff[4];                                                 \
    _Pragma("unroll")                                                     \
    for (int f = 0; f < 4; ++f) {                                         \
        int rr = wm * 64 + f * 16 + l15;                                  \
        aoff[f] = rr * 32 + ((l4 ^ ((rr >> 1) & 3)) << 3);                \
        int cc = wn * 64 + f * 16 + l15;                                  \
        boff[f] = cc * 32 + ((l4 ^ ((cc >> 1) & 3)) << 3);                \
    }                                                                     \
    floatx4 acc[4][4];                                                    \
    const floatx4 zero_ = {0.f, 0.f, 0.f, 0.f};                           \
    _Pragma("unroll")                                                     \
    for (int i = 0; i < 4; ++i)                                           \
        _Pragma("unroll")                                                 \
        for (int j = 0; j < 4; ++j) acc[i][j] = zero_;

// ---------------------------------------------------------------------------
// att (NT): att[b,m,n] = mask ? dot(c_hs[m,:], r_hs[n,:])/sqrt(E) : -1e12
// ---------------------------------------------------------------------------
__global__ __launch_bounds__(256, 2)
void mfma_att(const float* __restrict__ chs, const float* __restrict__ rhs,
              const int* __restrict__ cids, const int* __restrict__ rids,
              float* __restrict__ att) {
    __shared__ __bf16 Ahi[4096], Alo[4096], Bhi[4096], Blo[4096];
    const int b = blockIdx.z, m0 = blockIdx.x * 128, n0 = blockIdx.y * 128;
    TILE_SETUP();
    const float* Ap = chs + ((size_t)b * M_ + m0 + srow) * E_ + h * 16;
    const float* Bp = rhs + ((size_t)b * N_ + n0 + srow) * E_ + h * 16;

    for (int k0 = 0; k0 < E_; k0 += 32) {
        float va[16], vb[16];
        load16(Ap + k0, va);
        load16(Bp + k0, vb);
        __syncthreads();
        cvt_store16(va, Ahi, Alo, srow, h);
        cvt_store16(vb, Bhi, Blo, srow, h);
        __syncthreads();
        mfma_step(Ahi, Alo, Bhi, Blo, aoff, boff, acc);
    }

    bool rm[4];
#pragma unroll
    for (int fn = 0; fn < 4; ++fn)
        rm[fn] = rids[b * N_ + n0 + wn * 64 + fn * 16 + l15] != 0;
    float* Cb = att + (size_t)b * M_ * N_;
#pragma unroll
    for (int fm = 0; fm < 4; ++fm) {
        const int rbase = m0 + wm * 64 + fm * 16 + l4 * 4;
#pragma unroll
        for (int r = 0; r < 4; ++r) {
            const int row = rbase + r;
            const bool cm = cids[b * M_ + row] != 0;
#pragma unroll
            for (int fn = 0; fn < 4; ++fn) {
                float vv = (cm && rm[fn]) ? acc[fm][fn][r] * INV_SCALE : NEG_BIG;
                Cb[(size_t)row * N_ + n0 + wn * 64 + fn * 16 + l15] = vv;
            }
        }
    }
}

// ---------------------------------------------------------------------------
// NN (per batch): C[b] = A[b] (512x512) @ Bg[b] (512x768); B transposed via
// fp32 LDS bounce (scr[32][132], pad -> conflict-light column reads).
// ---------------------------------------------------------------------------
__global__ __launch_bounds__(256, 2)
void mfma_nn(const float* __restrict__ A, const float* __restrict__ Bg,
             float* __restrict__ C) {
    __shared__ __bf16 Ahi[4096], Alo[4096], Bhi[4096], Blo[4096];
    __shared__ float scr[32 * 132];
    const int b = blockIdx.z, m0 = blockIdx.x * 128, n0 = blockIdx.y * 128;
    TILE_SETUP();
    const float* Ap = A + ((size_t)b * M_ + m0 + srow) * 512 + h * 16;
    const float* Bbase = Bg + (size_t)b * 512 * E_ + n0;
    const int kk = tid >> 3, cseg = (tid & 7) * 16;

    for (int k0 = 0; k0 < 512; k0 += 32) {
        float va[16], wv[16];
        load16(Ap + k0, va);
        load16(Bbase + (size_t)(k0 + kk) * E_ + cseg, wv);
        __syncthreads();
        cvt_store16(va, Ahi, Alo, srow, h);
        *(float4*)&scr[kk * 132 + cseg]      = *(float4*)&wv[0];
        *(float4*)&scr[kk * 132 + cseg + 4]  = *(float4*)&wv[4];
        *(float4*)&scr[kk * 132 + cseg + 8]  = *(float4*)&wv[8];
        *(float4*)&scr[kk * 132 + cseg + 12] = *(float4*)&wv[12];
        __syncthreads();
        float vb[16];
#pragma unroll
        for (int j = 0; j < 16; ++j) vb[j] = scr[(h * 16 + j) * 132 + srow];
        cvt_store16(vb, Bhi, Blo, srow, h);
        __syncthreads();
        mfma_step(Ahi, Alo, Bhi, Blo, aoff, boff, acc);
    }

    float* Cb = C + (size_t)b * M_ * E_;
#pragma unroll
    for (int fm = 0; fm < 4; ++fm) {
        const int rbase = m0 + wm * 64 + fm * 16 + l4 * 4;
#pragma unroll
        for (int r = 0; r < 4; ++r)
#pragma unroll
            for (int fn = 0; fn < 4; ++fn)
                Cb[(size_t)(rbase + r) * E_ + n0 + wn * 64 + fn * 16 + l15] =
                    acc[fm][fn][r];
    }
}

// ---------------------------------------------------------------------------
// feat (NT vs WpreT): relu(submult(HAT,HS) @ W_pre + b_pre), with fused masked
// first/sum/max reduction into stats[b][3][768]. No bar matrix materialized.
// ---------------------------------------------------------------------------
__global__ __launch_bounds__(256, 2)
void mfma_feat(const float* __restrict__ HAT, const float* __restrict__ HS,
               const float* __restrict__ WT, const float* __restrict__ bias,
               const int* __restrict__ ids, float* __restrict__ stats) {
    __shared__ __bf16 Ahi[4096], Alo[4096], Bhi[4096], Blo[4096];
    const int m0 = blockIdx.x * 128, n0 = blockIdx.y * 128;
    TILE_SETUP();
    const float* Hp = HAT + (size_t)(m0 + srow) * E_ + h * 16;
    const float* Sp = HS + (size_t)(m0 + srow) * E_ + h * 16;
    const float* Wp = WT + (size_t)(n0 + srow) * 3840 + h * 16;

    for (int seg = 0; seg < 5; ++seg) {
        for (int e0 = 0; e0 < E_; e0 += 32) {
            float ha[16], sb[16], wv[16], f[16];
            load16(Hp + e0, ha);
            load16(Sp + e0, sb);
            load16(Wp + seg * E_ + e0, wv);
#pragma unroll
            for (int j = 0; j < 16; ++j) {
                float a = ha[j], bq = sb[j], d = a - bq;
                f[j] = (seg == 0) ? a : (seg == 1) ? bq : (seg == 2) ? d
                     : (seg == 3) ? a * bq : d * d;
            }
            __syncthreads();
            cvt_store16(f, Ahi, Alo, srow, h);
            cvt_store16(wv, Bhi, Blo, srow, h);
            __syncthreads();
            mfma_step(Ahi, Alo, Bhi, Blo, aoff, boff, acc);
        }
    }

    const int b = m0 >> 9;
    float bv[4];
#pragma unroll
    for (int fn = 0; fn < 4; ++fn)
        bv[fn] = bias[n0 + wn * 64 + fn * 16 + l15];
    float sum4[4] = {0.f, 0.f, 0.f, 0.f}, max4[4] = {0.f, 0.f, 0.f, 0.f};
#pragma unroll
    for (int fm = 0; fm < 4; ++fm) {
        const int rbase = m0 + wm * 64 + fm * 16 + l4 * 4;
#pragma unroll
        for (int r = 0; r < 4; ++r) {
            const int g = rbase + r;
            const bool valid = ids[g] != 0;
#pragma unroll
            for (int fn = 0; fn < 4; ++fn) {
                float v = fmaxf(acc[fm][fn][r] + bv[fn], 0.f);
                v = valid ? v : 0.f;
                sum4[fn] += v;
                max4[fn] = fmaxf(max4[fn], v);
                if ((g & 511) == 0)   // row 0 of this batch -> "first" stat
                    stats[b * 2304 + n0 + wn * 64 + fn * 16 + l15] = v;
            }
        }
    }
#pragma unroll
    for (int fn = 0; fn < 4; ++fn) {
        float s = sum4[fn];
        s += __shfl_xor(s, 16); s += __shfl_xor(s, 32);
        float mx = max4[fn];
        mx = fmaxf(mx, __shfl_xor(mx, 16)); mx = fmaxf(mx, __shfl_xor(mx, 32));
        if (l4 == 0) {
            const int col = n0 + wn * 64 + fn * 16 + l15;
            atomicAdd(&stats[b * 2304 + 768 + col], s);
            atomicMax((int*)&stats[b * 2304 + 1536 + col], __float_as_int(mx));
        }
    }
}

// ---------------------------------------------------------------------------
// W_pre [3840][768] -> WT [768][3840]
// ---------------------------------------------------------------------------
__global__ __launch_bounds__(256)
void transpose_w(const float* __restrict__ src, float* __restrict__ dst) {
    __shared__ float tile[32][33];
    const int c0 = blockIdx.x * 32, r0 = blockIdx.y * 32;
    const int tx = threadIdx.x & 31, ty = threadIdx.x >> 5;
#pragma unroll
    for (int i = 0; i < 32; i += 8)
        tile[ty + i][tx] = src[(size_t)(r0 + ty + i) * 768 + c0 + tx];
    __syncthreads();
#pragma unroll
    for (int i = 0; i < 32; i += 8)
        dst[(size_t)(c0 + ty + i) * 3840 + r0 + tx] = tile[tx][ty + i];
}

// ---------------------------------------------------------------------------
// Row softmax over last axis: one wave per row
// ---------------------------------------------------------------------------
__global__ __launch_bounds__(256)
void softmax_rows(const float* __restrict__ att, float* __restrict__ P) {
    const int wave = threadIdx.x >> 6;
    const int lane = threadIdx.x & 63;
    const size_t row = (size_t)blockIdx.x * 4 + wave;
    const float* x = att + row * N_;
    float v[8];
    float mx = -INFINITY;
#pragma unroll
    for (int i = 0; i < 8; ++i) { v[i] = x[lane + i * 64]; mx = fmaxf(mx, v[i]); }
#pragma unroll
    for (int off = 32; off; off >>= 1) mx = fmaxf(mx, __shfl_xor(mx, off));
    float s = 0.f;
#pragma unroll
    for (int i = 0; i < 8; ++i) { v[i] = __expf(v[i] - mx); s += v[i]; }
#pragma unroll
    for (int off = 32; off; off >>= 1) s += __shfl_xor(s, off);
    const float inv = 1.f / s;
    float* y = P + row * N_;
#pragma unroll
    for (int i = 0; i < 8; ++i) y[lane + i * 64] = v[i] * inv;
}

// ---------------------------------------------------------------------------
// Column softmax (over m) with transposed output P2t[b,n,m]
// ---------------------------------------------------------------------------
__global__ __launch_bounds__(256)
void softmax_cols_t(const float* __restrict__ att, float* __restrict__ P2t) {
    __shared__ float tile[512][17];
    __shared__ float red[16][16];
    __shared__ float invs[16];
    const int b = blockIdx.x, n0 = blockIdx.y * 16;
    const int tid = threadIdx.x;
    const int c = tid & 15, r = tid >> 4;
    const float* src = att + (size_t)b * M_ * N_ + n0;
#pragma unroll 4
    for (int i = 0; i < 32; ++i) {
        int m = r + i * 16;
        tile[m][c] = src[(size_t)m * N_ + c];
    }
    __syncthreads();
    float mx = -INFINITY;
    for (int m = r; m < 512; m += 16) mx = fmaxf(mx, tile[m][c]);
    red[r][c] = mx;
    __syncthreads();
    if (r == 0) {
        float m2 = red[0][c];
#pragma unroll
        for (int j = 1; j < 16; ++j) m2 = fmaxf(m2, red[j][c]);
        invs[c] = m2;
    }
    __syncthreads();
    const float cmx = invs[c];
    float s = 0.f;
    for (int m = r; m < 512; m += 16) {
        float e = __expf(tile[m][c] - cmx);
        tile[m][c] = e;
        s += e;
    }
    __syncthreads();
    red[r][c] = s;
    __syncthreads();
    if (r == 0) {
        float st = 0.f;
#pragma unroll
        for (int j = 0; j < 16; ++j) st += red[j][c];
        invs[c] = 1.f / st;
    }
    __syncthreads();
    float* dst = P2t + ((size_t)b * N_ + n0) * M_;
#pragma unroll 4
    for (int i = 0; i < 32; ++i) {
        int lin = tid + i * 256;
        int cc = lin >> 9;
        int m = lin & 511;
        dst[(size_t)cc * M_ + m] = tile[m][cc] * invs[cc];
    }
}

// ---------------------------------------------------------------------------
// stats -> m_vs[b][11520] (submult of [first, sum/cnt, max] features)
// ---------------------------------------------------------------------------
__global__ __launch_bounds__(256)
void ffprep_kernel(const float* __restrict__ sc, const float* __restrict__ sr,
                   const int* __restrict__ cids, const int* __restrict__ rids,
                   float* __restrict__ mv) {
    __shared__ int redc[4], redr[4];
    const int b = blockIdx.x, tid = threadIdx.x;
    int cc = 0, cr = 0;
    for (int m = tid; m < 512; m += 256) {
        cc += (cids[b * 512 + m] != 0);
        cr += (rids[b * 512 + m] != 0);
    }
#pragma unroll
    for (int off = 32; off; off >>= 1) {
        cc += __shfl_xor(cc, off);
        cr += __shfl_xor(cr, off);
    }
    if ((tid & 63) == 0) { redc[tid >> 6] = cc; redr[tid >> 6] = cr; }
    __syncthreads();
    const float invc = 1.f / (float)(redc[0] + redc[1] + redc[2] + redc[3]);
    const float invr = 1.f / (float)(redr[0] + redr[1] + redr[2] + redr[3]);
    const float* scb = sc + b * 2304;
    const float* srb = sr + b * 2304;
    float* mvb = mv + (size_t)b * 11520;
    for (int i = tid; i < 2304; i += 256) {
        float a = scb[i], r = srb[i];
        if (i >= 768 && i < 1536) { a *= invc; r *= invr; }
        float d = a - r;
        mvb[i]        = a;
        mvb[2304 + i] = r;
        mvb[4608 + i] = d;
        mvb[6912 + i] = a * r;
        mvb[9216 + i] = d * d;
    }
}

// ---------------------------------------------------------------------------
// hacc[b][j] += partial dot over e-chunk. Each W_ff1 element read ONCE:
// grid (3 j-slices, 16 e-chunks); 32 per-batch accumulators in VGPRs;
// mv reads are block-uniform -> scalar loads overlapping the VALU fmas.
// ---------------------------------------------------------------------------
__global__ __launch_bounds__(256)
void ff1_kernel(const float* __restrict__ mv, const float* __restrict__ W1,
                float* __restrict__ hacc) {
    const int j = blockIdx.x * 256 + threadIdx.x;   // 0..767
    const int e0 = blockIdx.y * 720;                // 16 chunks over 11520
    float acc[32];
#pragma unroll
    for (int b = 0; b < 32; ++b) acc[b] = 0.f;
    for (int ec = 0; ec < 720; ec += 4) {
        const float w0 = W1[(size_t)(e0 + ec + 0) * 768 + j];
        const float w1 = W1[(size_t)(e0 + ec + 1) * 768 + j];
        const float w2 = W1[(size_t)(e0 + ec + 2) * 768 + j];
        const float w3 = W1[(size_t)(e0 + ec + 3) * 768 + j];
#pragma unroll
        for (int b = 0; b < 32; ++b) {
            const float* mp = mv + (size_t)b * 11520 + e0 + ec;
            float a = acc[b];
            a = fmaf(mp[0], w0, a);
            a = fmaf(mp[1], w1, a);
            a = fmaf(mp[2], w2, a);
            a = fmaf(mp[3], w3, a);
            acc[b] = a;
        }
    }
#pragma unroll
    for (int b = 0; b < 32; ++b) atomicAdd(&hacc[b * 768 + j], acc[b]);
}

// ---------------------------------------------------------------------------
// scores[b] = b2 + sum_j relu(hacc + b1)[j] * W2[j]
// ---------------------------------------------------------------------------
__global__ __launch_bounds__(256)
void score_kernel(const float* __restrict__ hacc, const float* __restrict__ b1,
                  const float* __restrict__ W2, const float* __restrict__ b2,
                  float* __restrict__ out) {
    const int b = blockIdx.x, tid = threadIdx.x;
    float acc = 0.f;
    for (int j = tid; j < 768; j += 256)
        acc += fmaxf(hacc[b * 768 + j] + b1[j], 0.f) * W2[j];
#pragma unroll
    for (int off = 32; off; off >>= 1) acc += __shfl_xor(acc, off);
    __shared__ float red[4];
    if ((tid & 63) == 0) red[tid >> 6] = acc;
    __syncthreads();
    if (tid == 0) out[b] = red[0] + red[1] + red[2] + red[3] + b2[0];
}

// ---------------------------------------------------------------------------
extern "C" void kernel_launch(void* const* d_in, const int* in_sizes, int n_in,
                              void* d_out, int out_size, void* d_ws, size_t ws_size,
                              hipStream_t stream) {
    const int*   c_ids = (const int*)d_in[0];
    const int*   r_ids = (const int*)d_in[1];
    const float* c_hs  = (const float*)d_in[2];
    const float* r_hs  = (const float*)d_in[3];
    const float* W_pre = (const float*)d_in[4];
    const float* b_pre = (const float*)d_in[5];
    const float* W_ff1 = (const float*)d_in[6];
    const float* b_ff1 = (const float*)d_in[7];
    const float* W_ff2 = (const float*)d_in[8];
    const float* b_ff2 = (const float*)d_in[9];
    float* out = (float*)d_out;
    float* ws  = (float*)d_ws;

    const size_t ATT = (size_t)B_ * M_ * N_;   // 8,388,608
    const size_t CH  = (size_t)B_ * M_ * E_;   // 12,582,912

    // Aliased layout (floats). Peak 3*ATT + CH = 37,748,736 floats = 144.0 MiB:
    //   att  [0, ATT)          dead after softmaxes
    //   P1   [ATT, 2ATT)       dead after chat GEMM
    //   P2t  [2ATT, 3ATT)      dead after rhat GEMM
    //   chat [3ATT, 3ATT+CH)   dead after feat-c
    //   rhat [0, CH)           (over dead att + P1-head)
    //   WT   [CH, CH+2.95M)    (inside dead P1, written after chat GEMM)
    //   sc/sr/hacc/mv at [15532032, 16072704)  (inside dead P1)
    float* att  = ws;
    float* P1   = ws + ATT;
    float* P2t  = ws + 2 * ATT;
    float* chat = ws + 3 * ATT;
    float* rhat = ws;
    float* WT   = ws + CH;                 // 768*3840 = 2,949,120
    float* sc   = ws + 15532032;           // [B][3][768] = 73,728
    float* sr   = sc + 73728;
    float* hacc = sr + 73728;              // 24,576
    float* mv   = hacc + 24576;            // 368,640 (ends 16,072,704 < 2ATT)

    // 1. attention logits (masked, scaled)
    mfma_att<<<dim3(4, 4, 32), 256, 0, stream>>>(c_hs, r_hs, c_ids, r_ids, att);
    // 2. softmaxes
    softmax_rows  <<<dim3(B_ * M_ / 4), 256, 0, stream>>>(att, P1);
    softmax_cols_t<<<dim3(B_, 32), 256, 0, stream>>>(att, P2t);
    // 3a. c_hat = P1 @ r_hs   (P1 dead after)
    mfma_nn<<<dim3(4, 6, 32), 256, 0, stream>>>(P1, r_hs, chat);
    // P1 region now free: zero stats/hacc, build WT
    hipMemsetAsync(sc, 0, 172032 * sizeof(float), stream);
    transpose_w<<<dim3(24, 120), 256, 0, stream>>>(W_pre, WT);
    // 3b. r_hat = P2t @ c_hs  (P2t dead after)
    mfma_nn<<<dim3(4, 6, 32), 256, 0, stream>>>(P2t, c_hs, rhat);
    // 4. fused feature GEMM + masked first/sum/max reductions
    mfma_feat<<<dim3(128, 6), 256, 0, stream>>>(chat, c_hs, WT, b_pre, c_ids, sc);
    mfma_feat<<<dim3(128, 6), 256, 0, stream>>>(rhat, r_hs, WT, b_pre, r_ids, sr);
    // 5. FF head
    ffprep_kernel<<<dim3(32), 256, 0, stream>>>(sc, sr, c_ids, r_ids, mv);
    ff1_kernel<<<dim3(3, 16), 256, 0, stream>>>(mv, W_ff1, hacc);
    score_kernel<<<dim3(32), 256, 0, stream>>>(hacc, b_ff1, W_ff2, b_ff2, out);
}